// Round 1
// baseline (122.282 us; speedup 1.0000x reference)
//
#include <hip/hip_runtime.h>

// Problem constants (from reference)
#define B_      8
#define T_      316
#define CIN_    64
#define HF_     128
#define G_      32
#define E_      384
#define OUT_    8
#define STRIDE_ 4      // MINP / DOWN = 8/2

// Output layout (flat, in return order):
// patches: B*T*CIN*OUT*OUT = 10,354,688
// cx:      B*T             =      2,528
// cy:      B*T             =      2,528
// scale:   B*T             =      2,528
// fmap:    B*E*G*G         =  3,145,728
#define PATCH_SZ  10354688
#define CX_OFF    (PATCH_SZ)
#define CY_OFF    (CX_OFF + B_*T_)
#define SI_OFF    (CY_OFF + B_*T_)
#define FMAP_OFF  (SI_OFF + B_*T_)

// Kernel 1: per-batch owner map (LDS) + metadata outputs.
// One block per batch, 1024 threads (= G*G cells).
__global__ void meta_owner_kernel(const int* __restrict__ metas,
                                  float* __restrict__ out,
                                  int* __restrict__ owner)
{
    const int b   = blockIdx.x;
    const int tid = threadIdx.x;

    __shared__ int own[G_ * G_];
    own[tid] = -1;
    __syncthreads();

    if (tid < T_) {
        const int* m = metas + (b * T_ + tid) * 5;
        const int r = m[0], c = m[1], s = m[2], p = m[3];

        const float hs = (float)s * 0.5f;
        out[CX_OFF + b * T_ + tid] = (float)c + hs;
        out[CY_OFF + b * T_ + tid] = (float)r + hs;
        out[SI_OFF + b * T_ + tid] = (p == 16) ? 1.0f : ((p == 8) ? 2.0f : 0.0f);

        if (p > 0) {
            const int sl = (s < 4) ? s : 4;   // reference meshgrid is 4x4 masked by di<span
            for (int di = 0; di < sl; ++di) {
                for (int dj = 0; dj < sl; ++dj) {
                    const int rr = r + di, cc = c + dj;
                    if (rr < G_ && cc < G_)
                        own[rr * G_ + cc] = tid;  // cells are disjoint in this dataset
                }
            }
        }
    }
    __syncthreads();
    owner[b * G_ * G_ + tid] = own[tid];
}

// Kernel 2: bilinear patch extraction. One block per (b,t), 256 threads.
// thread = (channel phase 0..3, pixel 0..63); 16 channel iterations.
__global__ void patches_kernel(const float* __restrict__ x,
                               const int* __restrict__ metas,
                               float* __restrict__ out)
{
    const int bt  = blockIdx.x;            // b*T + t
    const int b   = bt / T_;
    const int tid = threadIdx.x;
    const int pix = tid & 63;
    const int i   = pix >> 3;
    const int j   = pix & 7;
    const int ch0 = tid >> 6;

    const int* m = metas + bt * 5;
    const int r = m[0], c = m[1], p = m[3];

    int pfi = p / 2;                       // p_feat = p_px // DOWN
    if (pfi < 1) pfi = 1;                  // jnp.maximum(p_feat, 1)
    const float pf    = (float)pfi;
    const float scale = pf * 0.125f;       // pf / OUT

    // rows (i -> wy), cols (j -> wx), exactly as reference
    const float reli = fminf(fmaxf(((float)i + 0.5f) * scale - 0.5f, 0.0f), pf - 1.0f);
    const float fi0  = floorf(reli);
    const float wy   = reli - fi0;
    const float fi1  = fminf(fi0 + 1.0f, pf - 1.0f);

    const float relj = fminf(fmaxf(((float)j + 0.5f) * scale - 0.5f, 0.0f), pf - 1.0f);
    const float fj0  = floorf(relj);
    const float wx   = relj - fj0;
    const float fj1  = fminf(fj0 + 1.0f, pf - 1.0f);

    const int y0 = r * STRIDE_ + (int)fi0;
    const int y1 = r * STRIDE_ + (int)fi1;
    const int x0 = c * STRIDE_ + (int)fj0;
    const int x1 = c * STRIDE_ + (int)fj1;

    const float* img = x + (size_t)b * CIN_ * HF_ * HF_;
    float*       po  = out + (size_t)bt * CIN_ * OUT_ * OUT_;

    const int r0 = y0 * HF_, r1 = y1 * HF_;

    for (int ch = ch0; ch < CIN_; ch += 4) {
        const float* ip = img + (size_t)ch * HF_ * HF_;
        const float v00 = ip[r0 + x0];
        const float v01 = ip[r0 + x1];
        const float v10 = ip[r1 + x0];
        const float v11 = ip[r1 + x1];
        const float top = v00 * (1.0f - wx) + v01 * wx;
        const float bot = v10 * (1.0f - wx) + v11 * wx;
        float val       = top * (1.0f - wy) + bot * wy;
        if (p <= 0) val = 0.0f;
        po[ch * (OUT_ * OUT_) + pix] = val;
    }
}

// Kernel 3: fmap gather. One thread per output element of (B,E,G,G).
__global__ void fmap_kernel(const float* __restrict__ tokens,
                            const int* __restrict__ owner,
                            float* __restrict__ fmap)
{
    const int idx  = blockIdx.x * blockDim.x + threadIdx.x;  // < B*E*G*G
    const int cell = idx & (G_ * G_ - 1);
    const int be   = idx >> 10;
    const int e    = be % E_;
    const int b    = be / E_;

    const int own = owner[b * G_ * G_ + cell];
    float v = 0.0f;
    if (own >= 0)
        v = tokens[((size_t)b * T_ + own) * E_ + e];
    fmap[idx] = v;
}

extern "C" void kernel_launch(void* const* d_in, const int* in_sizes, int n_in,
                              void* d_out, int out_size, void* d_ws, size_t ws_size,
                              hipStream_t stream) {
    const float* x_in   = (const float*)d_in[0];
    const float* tokens = (const float*)d_in[1];
    const int*   metas  = (const int*)d_in[2];
    float*       out    = (float*)d_out;
    int*         owner  = (int*)d_ws;     // B * G * G ints = 32 KB

    meta_owner_kernel<<<B_, G_ * G_, 0, stream>>>(metas, out, owner);
    patches_kernel<<<B_ * T_, 256, 0, stream>>>(x_in, metas, out);
    fmap_kernel<<<(B_ * E_ * G_ * G_) / 256, 256, 0, stream>>>(tokens, owner, out + FMAP_OFF);
}

// Round 2
// 116.426 us; speedup vs baseline: 1.0503x; 1.0503x over previous
//
#include <hip/hip_runtime.h>

// Problem constants (from reference)
#define B_      8
#define T_      316
#define CIN_    64
#define HF_     128
#define G_      32
#define E_      384
#define OUT_    8
#define STRIDE_ 4      // MINP / DOWN = 8/2

// Output layout (flat, in return order)
#define PATCH_SZ  10354688           // B*T*CIN*OUT*OUT
#define CX_OFF    (PATCH_SZ)
#define CY_OFF    (CX_OFF + B_*T_)
#define SI_OFF    (CY_OFF + B_*T_)
#define FMAP_OFF  (SI_OFF + B_*T_)

// Kernel 1: per-batch owner map (LDS) + metadata outputs.
__global__ void meta_owner_kernel(const int* __restrict__ metas,
                                  float* __restrict__ out,
                                  int* __restrict__ owner)
{
    const int b   = blockIdx.x;
    const int tid = threadIdx.x;

    __shared__ int own[G_ * G_];
    own[tid] = -1;
    __syncthreads();

    if (tid < T_) {
        const int* m = metas + (b * T_ + tid) * 5;
        const int r = m[0], c = m[1], s = m[2], p = m[3];

        const float hs = (float)s * 0.5f;
        out[CX_OFF + b * T_ + tid] = (float)c + hs;
        out[CY_OFF + b * T_ + tid] = (float)r + hs;
        out[SI_OFF + b * T_ + tid] = (p == 16) ? 1.0f : ((p == 8) ? 2.0f : 0.0f);

        if (p > 0) {
            const int sl = (s < 4) ? s : 4;   // ref meshgrid is 4x4 masked by di<span
            for (int di = 0; di < sl; ++di)
                for (int dj = 0; dj < sl; ++dj) {
                    const int rr = r + di, cc = c + dj;
                    if (rr < G_ && cc < G_)
                        own[rr * G_ + cc] = tid;  // cells are disjoint in this dataset
                }
        }
    }
    __syncthreads();
    owner[b * G_ * G_ + tid] = own[tid];
}

// Kernel 2: patch extraction. One block per (b,t), 256 threads.
// p==16 => pf=8 => rel=i exactly => pure 8x8 region copy (float4 path).
// else  => general bilinear (80/316 tokens per batch).
__global__ void patches_kernel(const float* __restrict__ x,
                               const int* __restrict__ metas,
                               float* __restrict__ out)
{
    const int bt  = blockIdx.x;            // b*T + t
    const int b   = bt / T_;
    const int tid = threadIdx.x;

    const int* m = metas + bt * 5;
    const int r = m[0], c = m[1], p = m[3];

    const float* img = x + (size_t)b * CIN_ * HF_ * HF_;
    float*       po  = out + (size_t)bt * CIN_ * OUT_ * OUT_;

    if (p == 16) {
        // unit u = ch*16 + i*2 + j4 ; 1024 units, 4 per thread
        const float* src = img + (size_t)(r * STRIDE_) * HF_ + c * STRIDE_;
        float4* po4 = (float4*)po;
#pragma unroll
        for (int k = 0; k < 4; ++k) {
            const int u   = tid + k * 256;
            const int ch  = u >> 4;
            const int rem = u & 15;
            const int i   = rem >> 1;
            const int j4  = rem & 1;
            const float4 v = *(const float4*)(src + (size_t)ch * (HF_ * HF_) + i * HF_ + j4 * 4);
            po4[u] = v;
        }
        return;
    }

    // General bilinear path
    const int pix = tid & 63;
    const int i   = pix >> 3;
    const int j   = pix & 7;
    const int ch0 = tid >> 6;

    int pfi = p / 2;
    if (pfi < 1) pfi = 1;
    const float pf    = (float)pfi;
    const float scale = pf * 0.125f;

    const float reli = fminf(fmaxf(((float)i + 0.5f) * scale - 0.5f, 0.0f), pf - 1.0f);
    const float fi0  = floorf(reli);
    const float wy   = reli - fi0;
    const float fi1  = fminf(fi0 + 1.0f, pf - 1.0f);

    const float relj = fminf(fmaxf(((float)j + 0.5f) * scale - 0.5f, 0.0f), pf - 1.0f);
    const float fj0  = floorf(relj);
    const float wx   = relj - fj0;
    const float fj1  = fminf(fj0 + 1.0f, pf - 1.0f);

    const int y0 = r * STRIDE_ + (int)fi0;
    const int y1 = r * STRIDE_ + (int)fi1;
    const int x0 = c * STRIDE_ + (int)fj0;
    const int x1 = c * STRIDE_ + (int)fj1;

    const int r0 = y0 * HF_, r1 = y1 * HF_;

    for (int ch = ch0; ch < CIN_; ch += 4) {
        const float* ip = img + (size_t)ch * (HF_ * HF_);
        const float v00 = ip[r0 + x0];
        const float v01 = ip[r0 + x1];
        const float v10 = ip[r1 + x0];
        const float v11 = ip[r1 + x1];
        const float top = v00 * (1.0f - wx) + v01 * wx;
        const float bot = v10 * (1.0f - wx) + v11 * wx;
        float val       = top * (1.0f - wy) + bot * wy;
        if (p <= 0) val = 0.0f;
        po[ch * (OUT_ * OUT_) + pix] = val;
    }
}

// Kernel 3: fmap gather. Block = (b, group of 8 e-values), 256 threads.
// Thread owns 4 consecutive cells (int4 owner load, float4 writes).
// Token-row cache lines are L1-reused across the 8 e iterations.
#define EG_ 8
__global__ void fmap_kernel(const float* __restrict__ tokens,
                            const int* __restrict__ owner,
                            float* __restrict__ fmap)
{
    const int b  = blockIdx.x / (E_ / EG_);
    const int eg = blockIdx.x % (E_ / EG_);
    const int t  = threadIdx.x;

    const int4 own = *(const int4*)(owner + b * (G_ * G_) + 4 * t);
    const float* tok = tokens + (size_t)b * T_ * E_ + eg * EG_;
    float4* fm = (float4*)(fmap + (size_t)b * E_ * (G_ * G_) + (size_t)eg * EG_ * (G_ * G_));

#pragma unroll
    for (int e = 0; e < EG_; ++e) {
        float4 v;
        v.x = (own.x >= 0) ? tok[(size_t)own.x * E_ + e] : 0.0f;
        v.y = (own.y >= 0) ? tok[(size_t)own.y * E_ + e] : 0.0f;
        v.z = (own.z >= 0) ? tok[(size_t)own.z * E_ + e] : 0.0f;
        v.w = (own.w >= 0) ? tok[(size_t)own.w * E_ + e] : 0.0f;
        fm[e * 256 + t] = v;
    }
}

extern "C" void kernel_launch(void* const* d_in, const int* in_sizes, int n_in,
                              void* d_out, int out_size, void* d_ws, size_t ws_size,
                              hipStream_t stream) {
    const float* x_in   = (const float*)d_in[0];
    const float* tokens = (const float*)d_in[1];
    const int*   metas  = (const int*)d_in[2];
    float*       out    = (float*)d_out;
    int*         owner  = (int*)d_ws;     // B * G * G ints = 32 KB

    meta_owner_kernel<<<B_, G_ * G_, 0, stream>>>(metas, out, owner);
    patches_kernel<<<B_ * T_, 256, 0, stream>>>(x_in, metas, out);
    fmap_kernel<<<B_ * (E_ / EG_), 256, 0, stream>>>(tokens, owner, out + FMAP_OFF);
}

// Round 3
// 106.898 us; speedup vs baseline: 1.1439x; 1.0891x over previous
//
#include <hip/hip_runtime.h>

// Problem constants (from reference)
#define B_      8
#define T_      316
#define CIN_    64
#define HF_     128
#define G_      32
#define E_      384
#define OUT_    8
#define STRIDE_ 4      // MINP / DOWN = 8/2

// Output layout (flat, in return order)
#define PATCH_SZ  10354688           // B*T*CIN*OUT*OUT
#define CX_OFF    (PATCH_SZ)
#define CY_OFF    (CX_OFF + B_*T_)
#define SI_OFF    (CY_OFF + B_*T_)
#define FMAP_OFF  (SI_OFF + B_*T_)

#define EG_   16                     // e-values per fmap block
#define NF_   (B_ * (E_ / EG_))     // 192 fmap blocks
#define NP_   (B_ * T_)             // 2528 patch blocks

__device__ __forceinline__ void load16(float* d, const float* p, bool ok)
{
    if (ok) {
        const float4* q = (const float4*)p;
#pragma unroll
        for (int k = 0; k < 4; ++k) {
            const float4 v = q[k];
            d[4*k+0] = v.x; d[4*k+1] = v.y; d[4*k+2] = v.z; d[4*k+3] = v.w;
        }
    } else {
#pragma unroll
        for (int k = 0; k < 16; ++k) d[k] = 0.0f;
    }
}

__global__ void fused_kernel(const float* __restrict__ x,
                             const float* __restrict__ tokens,
                             const int* __restrict__ metas,
                             float* __restrict__ out)
{
    const int blk = blockIdx.x;
    const int tid = threadIdx.x;

    if (blk < NF_) {
        // ---------------- fmap + metadata path ----------------
        const int b  = blk / (E_ / EG_);
        const int eg = blk % (E_ / EG_);

        __shared__ int own[G_ * G_];
#pragma unroll
        for (int k = 0; k < 4; ++k) own[tid + k * 256] = -1;
        __syncthreads();

        for (int t = tid; t < T_; t += 256) {
            const int* m = metas + (b * T_ + t) * 5;
            const int r = m[0], c = m[1], s = m[2], p = m[3];

            if (eg == 0) {
                const float hs = (float)s * 0.5f;
                out[CX_OFF + b * T_ + t] = (float)c + hs;
                out[CY_OFF + b * T_ + t] = (float)r + hs;
                out[SI_OFF + b * T_ + t] = (p == 16) ? 1.0f : ((p == 8) ? 2.0f : 0.0f);
            }
            if (p > 0) {
                const int sl = (s < 4) ? s : 4;
                for (int di = 0; di < sl; ++di)
                    for (int dj = 0; dj < sl; ++dj) {
                        const int rr = r + di, cc = c + dj;
                        if (rr < G_ && cc < G_)
                            own[rr * G_ + cc] = t;   // cells disjoint in this dataset
                    }
            }
        }
        __syncthreads();

        // thread owns 4 consecutive cells; 16 e-values
        const int4 o = *(const int4*)(own + 4 * tid);
        const float* tok = tokens + (size_t)b * T_ * E_ + eg * EG_;

        float a0[16], a1[16], a2[16], a3[16];
        load16(a0, tok + (size_t)o.x * E_, o.x >= 0);
        load16(a1, tok + (size_t)o.y * E_, o.y >= 0);
        load16(a2, tok + (size_t)o.z * E_, o.z >= 0);
        load16(a3, tok + (size_t)o.w * E_, o.w >= 0);

        float4* fm = (float4*)(out + FMAP_OFF + (size_t)b * E_ * (G_ * G_)
                                              + (size_t)eg * EG_ * (G_ * G_));
#pragma unroll
        for (int e = 0; e < EG_; ++e) {
            float4 v; v.x = a0[e]; v.y = a1[e]; v.z = a2[e]; v.w = a3[e];
            fm[e * 256 + tid] = v;
        }
        return;
    }

    // ---------------- patches path ----------------
    const int bt = blk - NF_;              // b*T + t
    const int b  = bt / T_;

    const int* m = metas + bt * 5;
    const int r = m[0], c = m[1], p = m[3];

    const float* img = x + (size_t)b * CIN_ * HF_ * HF_;
    float*       po  = out + (size_t)bt * CIN_ * OUT_ * OUT_;

    if (p == 16) {
        // pf=8 -> rel=i exactly -> pure 8x8 region copy (float4 path)
        const float* src = img + (size_t)(r * STRIDE_) * HF_ + c * STRIDE_;
        float4* po4 = (float4*)po;
#pragma unroll
        for (int k = 0; k < 4; ++k) {
            const int u   = tid + k * 256;
            const int ch  = u >> 4;
            const int rem = u & 15;
            const int i   = rem >> 1;
            const int j4  = rem & 1;
            po4[u] = *(const float4*)(src + (size_t)ch * (HF_ * HF_) + i * HF_ + j4 * 4);
        }
        return;
    }

    // General bilinear path (p != 16)
    const int pix = tid & 63;
    const int i   = pix >> 3;
    const int j   = pix & 7;
    const int ch0 = tid >> 6;

    int pfi = p / 2;
    if (pfi < 1) pfi = 1;
    const float pf    = (float)pfi;
    const float scale = pf * 0.125f;

    const float reli = fminf(fmaxf(((float)i + 0.5f) * scale - 0.5f, 0.0f), pf - 1.0f);
    const float fi0  = floorf(reli);
    const float wy   = reli - fi0;
    const float fi1  = fminf(fi0 + 1.0f, pf - 1.0f);

    const float relj = fminf(fmaxf(((float)j + 0.5f) * scale - 0.5f, 0.0f), pf - 1.0f);
    const float fj0  = floorf(relj);
    const float wx   = relj - fj0;
    const float fj1  = fminf(fj0 + 1.0f, pf - 1.0f);

    const int y0 = r * STRIDE_ + (int)fi0;
    const int y1 = r * STRIDE_ + (int)fi1;
    const int x0 = c * STRIDE_ + (int)fj0;
    const int x1 = c * STRIDE_ + (int)fj1;

    const int r0 = y0 * HF_, r1 = y1 * HF_;

    for (int ch = ch0; ch < CIN_; ch += 4) {
        const float* ip = img + (size_t)ch * (HF_ * HF_);
        const float v00 = ip[r0 + x0];
        const float v01 = ip[r0 + x1];
        const float v10 = ip[r1 + x0];
        const float v11 = ip[r1 + x1];
        const float top = v00 * (1.0f - wx) + v01 * wx;
        const float bot = v10 * (1.0f - wx) + v11 * wx;
        float val       = top * (1.0f - wy) + bot * wy;
        if (p <= 0) val = 0.0f;
        po[ch * (OUT_ * OUT_) + pix] = val;
    }
}

extern "C" void kernel_launch(void* const* d_in, const int* in_sizes, int n_in,
                              void* d_out, int out_size, void* d_ws, size_t ws_size,
                              hipStream_t stream) {
    const float* x_in   = (const float*)d_in[0];
    const float* tokens = (const float*)d_in[1];
    const int*   metas  = (const int*)d_in[2];
    float*       out    = (float*)d_out;

    fused_kernel<<<NF_ + NP_, 256, 0, stream>>>(x_in, tokens, metas, out);
}